// Round 6
// baseline (33.254 us; speedup 1.0000x reference)
//
#include <hip/hip_runtime.h>

// ROIAlign (aligned=True, TF crop_and_resize semantics), NHWC fp32.
// inputs: [2,100,100,256] f32; boxes: [1024,4] f32 (x0,y0,x1,y1);
// box_inds: [1024] i32; out: [1024,7,7,256] f32.
//
// Round-6 structure:
//  - kernel A: ballot-sort the 1024 boxes by spatial bin (image*4 + y-band)
//    so each XCD chunk's boxes share a ~3.3 MB map slice (fits 4 MB L2).
//  - kernel B: block = HALF-BOX (2048 blocks x 4 waves). Phase 1 computes the
//    box's 7 row-metas + 7 col-metas (separable merged bilinear: nr*nc unique
//    corners, nr,nc in {2..4}) ONCE into LDS; phase 2 waves loop ~6 pixels
//    each, gathering f32x4 per lane. Kills the 50176x-redundant uniform VALU.

constexpr int   H_IN  = 100;
constexpr int   W_IN  = 100;
constexpr int   C_IN  = 256;
constexpr int   OUT_H = 7;
constexpr int   OUT_W = 7;
constexpr int   NPIX  = OUT_H * OUT_W;   // 49
constexpr int   NBOX  = 1024;
constexpr float SCALE = 0.125f;

typedef float f32x4 __attribute__((ext_vector_type(4)));

// ---------------- kernel A: spatial box sort (1 block, 1024 threads) -------
__global__ __launch_bounds__(1024) void sort_boxes_kernel(
    const float* __restrict__ boxes,
    const int*   __restrict__ box_inds,
    int*         __restrict__ perm)       // d_ws, NBOX ints
{
    const int tid  = threadIdx.x;
    const int wave = tid >> 6;
    const int lane = tid & 63;

    const float y0 = boxes[tid * 4 + 1] * SCALE;
    const float y1 = boxes[tid * 4 + 3] * SCALE;
    const float cy = 0.5f * (y0 + y1);
    int band = (int)(cy * (1.0f / 25.0f));
    band = min(max(band, 0), 3);
    const int bin = box_inds[tid] * 4 + band;   // 0..7

    __shared__ int whist[16][8];   // per-wave bin counts
    __shared__ int wbase[16][8];   // exclusive scan, bin-major

    int wrank = 0;
    const unsigned long long ltmask = (lane == 63) ? ~0ull >> 1
                                                   : (1ull << lane) - 1;
#pragma unroll
    for (int k = 0; k < 8; ++k) {
        const unsigned long long bal = __ballot(bin == k);
        if (bin == k) wrank = __popcll(bal & ltmask);
        if (lane == 0) whist[wave][k] = __popcll(bal);
    }
    __syncthreads();

    if (tid == 0) {
        int acc = 0;
        for (int k = 0; k < 8; ++k)
            for (int w = 0; w < 16; ++w) {
                wbase[w][k] = acc;
                acc += whist[w][k];
            }
    }
    __syncthreads();

    perm[wbase[wave][bin] + wrank] = tid;
}

// ---------------- merged bilinear per-dimension metadata -------------------
__device__ __forceinline__ int merge_dim(float s0, float s1, int LIM,
                                         int* idx, float* w)
{
    const float f0 = floorf(s0);
    const float f1 = floorf(s1);
    const float t0 = s0 - f0;
    const float t1 = s1 - f1;
    const float va = (s0 >= 0.0f && s0 <= (float)(LIM - 1)) ? 1.0f : 0.0f;
    const float vb = (s1 >= 0.0f && s1 <= (float)(LIM - 1)) ? 1.0f : 0.0f;
    const int i0 = (int)f0;
    const int i1 = (int)f1;

    int n;
    if (i1 == i0) {                 // both samples in the same cell
        n = 2;
        idx[0] = i0;     w[0] = va * (1.0f - t0) + vb * (1.0f - t1);
        idx[1] = i0 + 1; w[1] = va * t0 + vb * t1;
        idx[2] = i0;     w[2] = 0.0f;
        idx[3] = i0;     w[3] = 0.0f;
    } else if (i1 == i0 + 1) {      // adjacent cells, shared middle line
        n = 3;
        idx[0] = i0;     w[0] = va * (1.0f - t0);
        idx[1] = i0 + 1; w[1] = va * t0 + vb * (1.0f - t1);
        idx[2] = i0 + 2; w[2] = vb * t1;
        idx[3] = i0;     w[3] = 0.0f;
    } else {                        // disjoint cells
        n = 4;
        idx[0] = i0;     w[0] = va * (1.0f - t0);
        idx[1] = i0 + 1; w[1] = va * t0;
        idx[2] = i1;     w[2] = vb * (1.0f - t1);
        idx[3] = i1 + 1; w[3] = vb * t1;
    }
#pragma unroll
    for (int k = 0; k < 4; ++k)     // clamp for addressing (weights already 0 when invalid)
        idx[k] = min(max(idx[k], 0), LIM - 1);
    return n;
}

// ---------------- gather: nr*nc unique corners, batched loads --------------
template<int NR, int NC>
__device__ __forceinline__ f32x4 gather(const float* __restrict__ base,
                                        const int* ro, const int* co,
                                        const float* wr, const float* wc,
                                        int c4)
{
    f32x4 v[NR * NC];
#pragma unroll
    for (int i = 0; i < NR; ++i)
#pragma unroll
        for (int j = 0; j < NC; ++j)
            v[i * NC + j] = *(const f32x4*)(base + (size_t)(ro[i] + co[j] + c4));

    f32x4 acc = {0.f, 0.f, 0.f, 0.f};
#pragma unroll
    for (int i = 0; i < NR; ++i)
#pragma unroll
        for (int j = 0; j < NC; ++j)
            acc += v[i * NC + j] * (wr[i] * wc[j]);
    return acc;
}

// ---------------- kernel B: half-box blocks --------------------------------
__global__ __launch_bounds__(256, 4) void roi_align_kernel(
    const float* __restrict__ inputs,
    const float* __restrict__ boxes,
    const int*   __restrict__ box_inds,
    const int*   __restrict__ perm,
    float*       __restrict__ out)
{
    const int tid  = threadIdx.x;
    const int lane = tid & 63;
    const int wv   = tid >> 6;

    // XCD-chunked swizzle: 2048 blocks, 256 consecutive lbids per XCD;
    // lbid pairs (same box) stay on one XCD.
    const int nchunk = gridDim.x >> 3;
    const int lbid   = (blockIdx.x & 7) * nchunk + (blockIdx.x >> 3);
    const int bs     = lbid >> 1;               // sorted box slot
    const int h      = lbid & 1;                // half index

    const int b = __builtin_amdgcn_readfirstlane(perm[bs]);
    const int n = __builtin_amdgcn_readfirstlane(box_inds[b]);

    __shared__ int4   s_roff[OUT_H];
    __shared__ float4 s_rw[OUT_H];
    __shared__ int4   s_coff[OUT_W];
    __shared__ float4 s_cw[OUT_W];
    __shared__ int    s_nr[OUT_H];
    __shared__ int    s_nc[OUT_W];

    // Phase 1: 14 threads compute the box's row/col metadata once.
    if (tid < 14) {
        const float bx0 = boxes[b * 4 + 0] * SCALE;
        const float by0 = boxes[b * 4 + 1] * SCALE;
        const float bx1 = boxes[b * 4 + 2] * SCALE;
        const float by1 = boxes[b * 4 + 3] * SCALE;
        const float sw  = (bx1 - bx0) * (1.0f / 14.0f);
        const float sh  = (by1 - by0) * (1.0f / 14.0f);

        int   idx[4];
        float wgt[4];
        if (tid < 7) {
            const int   oy = tid;
            const float s0 = by0 + sh * ((float)(oy * 2) + 0.5f) - 0.5f;
            const int   nr = merge_dim(s0, s0 + sh, H_IN, idx, wgt);
            int4 off; float4 wq;
#pragma unroll
            for (int k = 0; k < 4; ++k) {
                ((int*)&off)[k]   = idx[k] * (W_IN * C_IN);   // premult row stride
                ((float*)&wq)[k]  = wgt[k] * 0.25f;           // fold 1/4 sample avg
            }
            s_roff[oy] = off; s_rw[oy] = wq; s_nr[oy] = nr;
        } else {
            const int   ox = tid - 7;
            const float s0 = bx0 + sw * ((float)(ox * 2) + 0.5f) - 0.5f;
            const int   nc = merge_dim(s0, s0 + sw, W_IN, idx, wgt);
            int4 off; float4 wq;
#pragma unroll
            for (int k = 0; k < 4; ++k) {
                ((int*)&off)[k]   = idx[k] * C_IN;            // premult col stride
                ((float*)&wq)[k]  = wgt[k];
            }
            s_coff[ox] = off; s_cw[ox] = wq; s_nc[ox] = nc;
        }
    }
    __syncthreads();

    const float* base = inputs + (size_t)n * (H_IN * W_IN * C_IN);
    const int    c4   = lane * 4;
    const int    start = h * 25;
    const int    pend  = h ? NPIX : 25;

    for (int k = 0; k < 7; ++k) {
        const int pix = start + wv + 4 * k;
        if (pix >= pend) break;
        const int oy = (pix * 37) >> 8;        // exact /7 for 0..48
        const int ox = pix - oy * 7;

        int4   roI = s_roff[oy];
        float4 rwV = s_rw[oy];
        int4   coI = s_coff[ox];
        float4 cwV = s_cw[ox];
        const int* ro   = (const int*)&roI;
        const float* wr = (const float*)&rwV;
        const int* co   = (const int*)&coI;
        const float* wc = (const float*)&cwV;

        const int sel = __builtin_amdgcn_readfirstlane(
            (s_nr[oy] - 2) * 3 + (s_nc[ox] - 2));

        f32x4 acc;
        switch (sel) {
            case 0: acc = gather<2, 2>(base, ro, co, wr, wc, c4); break;
            case 1: acc = gather<2, 3>(base, ro, co, wr, wc, c4); break;
            case 2: acc = gather<2, 4>(base, ro, co, wr, wc, c4); break;
            case 3: acc = gather<3, 2>(base, ro, co, wr, wc, c4); break;
            case 4: acc = gather<3, 3>(base, ro, co, wr, wc, c4); break;
            case 5: acc = gather<3, 4>(base, ro, co, wr, wc, c4); break;
            case 6: acc = gather<4, 2>(base, ro, co, wr, wc, c4); break;
            case 7: acc = gather<4, 3>(base, ro, co, wr, wc, c4); break;
            default: acc = gather<4, 4>(base, ro, co, wr, wc, c4); break;
        }

        float* op = out + ((size_t)b * NPIX + pix) * C_IN + c4;
        __builtin_nontemporal_store(acc, (f32x4*)op);
    }
}

extern "C" void kernel_launch(void* const* d_in, const int* in_sizes, int n_in,
                              void* d_out, int out_size, void* d_ws, size_t ws_size,
                              hipStream_t stream) {
    const float* inputs   = (const float*)d_in[0];
    const float* boxes    = (const float*)d_in[1];
    const int*   box_inds = (const int*)d_in[2];
    float*       out      = (float*)d_out;
    int*         perm     = (int*)d_ws;           // NBOX ints

    sort_boxes_kernel<<<1, NBOX, 0, stream>>>(boxes, box_inds, perm);
    roi_align_kernel<<<NBOX * 2, 256, 0, stream>>>(inputs, boxes, box_inds, perm, out);
}

// Round 7
// 31.164 us; speedup vs baseline: 1.0671x; 1.0671x over previous
//
#include <hip/hip_runtime.h>

// ROIAlign (aligned=True, TF crop_and_resize semantics), NHWC fp32.
// inputs: [2,100,100,256] f32; boxes: [1024,4] f32 (x0,y0,x1,y1);
// box_inds: [1024] i32; out: [1024,7,7,256] f32.
//
// Round-7 structure (3 kernels):
//  A  sort_boxes:  ballot-sort 1024 boxes by (image*4 + y-band) -> perm,
//                  so each XCD chunk's boxes share a ~3.3 MB map slice (L2-fit).
//  A2 meta:        per sorted slot, precompute 7 row-metas + 7 col-metas
//                  (separable merged bilinear; nr,nc in {2..4}); offsets are
//                  absolute (image base folded into row offs), weights have
//                  the 1/4 sample-average folded; (nr-2)/(nc-2) packed into
//                  the free low bits of the 256-multiple offsets. -> d_ws.
//  B  main:        ONE WAVE PER OUTPUT PIXEL (50176 waves for TLP); per wave:
//                  uniform meta loads, scalar switch, nr*nc f32x4 gathers.

constexpr int   H_IN  = 100;
constexpr int   W_IN  = 100;
constexpr int   C_IN  = 256;
constexpr int   OUT_H = 7;
constexpr int   OUT_W = 7;
constexpr int   NPIX  = OUT_H * OUT_W;   // 49
constexpr int   NBOX  = 1024;
constexpr float SCALE = 0.125f;

typedef float f32x4 __attribute__((ext_vector_type(4)));

struct Meta { int4 off; float4 w; };     // 32 B

// ws layout: perm int[1024] @0 ; rmeta Meta[7168] @4096 ; cmeta Meta[7168] @233472
constexpr int RMETA_OFF = 4096;
constexpr int CMETA_OFF = 4096 + 7168 * 32;

// ---------------- kernel A: spatial box sort (1 block, 1024 threads) -------
__global__ __launch_bounds__(1024) void sort_boxes_kernel(
    const float* __restrict__ boxes,
    const int*   __restrict__ box_inds,
    int*         __restrict__ perm)
{
    const int tid  = threadIdx.x;
    const int wave = tid >> 6;
    const int lane = tid & 63;

    const float y0 = boxes[tid * 4 + 1] * SCALE;
    const float y1 = boxes[tid * 4 + 3] * SCALE;
    const float cy = 0.5f * (y0 + y1);
    int band = (int)(cy * (1.0f / 25.0f));
    band = min(max(band, 0), 3);
    const int bin = box_inds[tid] * 4 + band;   // 0..7

    __shared__ int whist[16][8];
    __shared__ int wbase[16][8];

    int wrank = 0;
    const unsigned long long ltmask = (lane == 63) ? ~0ull >> 1
                                                   : (1ull << lane) - 1;
#pragma unroll
    for (int k = 0; k < 8; ++k) {
        const unsigned long long bal = __ballot(bin == k);
        if (bin == k) wrank = __popcll(bal & ltmask);
        if (lane == 0) whist[wave][k] = __popcll(bal);
    }
    __syncthreads();

    if (tid == 0) {
        int acc = 0;
        for (int k = 0; k < 8; ++k)
            for (int w = 0; w < 16; ++w) {
                wbase[w][k] = acc;
                acc += whist[w][k];
            }
    }
    __syncthreads();

    perm[wbase[wave][bin] + wrank] = tid;
}

// ---------------- merged bilinear per-dimension metadata -------------------
__device__ __forceinline__ int merge_dim(float s0, float s1, int LIM,
                                         int* idx, float* w)
{
    const float f0 = floorf(s0);
    const float f1 = floorf(s1);
    const float t0 = s0 - f0;
    const float t1 = s1 - f1;
    const float va = (s0 >= 0.0f && s0 <= (float)(LIM - 1)) ? 1.0f : 0.0f;
    const float vb = (s1 >= 0.0f && s1 <= (float)(LIM - 1)) ? 1.0f : 0.0f;
    const int i0 = (int)f0;
    const int i1 = (int)f1;

    int n;
    if (i1 == i0) {
        n = 2;
        idx[0] = i0;     w[0] = va * (1.0f - t0) + vb * (1.0f - t1);
        idx[1] = i0 + 1; w[1] = va * t0 + vb * t1;
        idx[2] = i0;     w[2] = 0.0f;
        idx[3] = i0;     w[3] = 0.0f;
    } else if (i1 == i0 + 1) {
        n = 3;
        idx[0] = i0;     w[0] = va * (1.0f - t0);
        idx[1] = i0 + 1; w[1] = va * t0 + vb * (1.0f - t1);
        idx[2] = i0 + 2; w[2] = vb * t1;
        idx[3] = i0;     w[3] = 0.0f;
    } else {
        n = 4;
        idx[0] = i0;     w[0] = va * (1.0f - t0);
        idx[1] = i0 + 1; w[1] = va * t0;
        idx[2] = i1;     w[2] = vb * (1.0f - t1);
        idx[3] = i1 + 1; w[3] = vb * t1;
    }
#pragma unroll
    for (int k = 0; k < 4; ++k)
        idx[k] = min(max(idx[k], 0), LIM - 1);
    return n;
}

// ---------------- kernel A2: per-slot metadata (56 blocks x 256) -----------
__global__ __launch_bounds__(256) void meta_kernel(
    const float* __restrict__ boxes,
    const int*   __restrict__ box_inds,
    const int*   __restrict__ perm,
    Meta*        __restrict__ rmeta,
    Meta*        __restrict__ cmeta)
{
    const int t = blockIdx.x * 256 + threadIdx.x;   // 0..14335
    if (t >= NBOX * 14) return;
    const int slot = t / 14;
    const int d    = t - slot * 14;

    const int b = perm[slot];
    const int n = box_inds[b];

    const float bx0 = boxes[b * 4 + 0] * SCALE;
    const float by0 = boxes[b * 4 + 1] * SCALE;
    const float bx1 = boxes[b * 4 + 2] * SCALE;
    const float by1 = boxes[b * 4 + 3] * SCALE;
    const float sw  = (bx1 - bx0) * (1.0f / 14.0f);
    const float sh  = (by1 - by0) * (1.0f / 14.0f);

    int idx[4]; float wgt[4];
    Meta m;
    if (d < 7) {                       // row meta: absolute offsets (image base folded)
        const float s0 = by0 + sh * ((float)(d * 2) + 0.5f) - 0.5f;
        const int   nr = merge_dim(s0, s0 + sh, H_IN, idx, wgt);
#pragma unroll
        for (int k = 0; k < 4; ++k) {
            ((int*)&m.off)[k]  = n * (H_IN * W_IN * C_IN) + idx[k] * (W_IN * C_IN);
            ((float*)&m.w)[k]  = wgt[k] * 0.25f;        // fold 1/4 sample average
        }
        m.off.x |= (nr - 2);           // offsets are multiples of 256 -> low bits free
        rmeta[slot * 7 + d] = m;
    } else {                           // col meta
        const int   ox = d - 7;
        const float s0 = bx0 + sw * ((float)(ox * 2) + 0.5f) - 0.5f;
        const int   nc = merge_dim(s0, s0 + sw, W_IN, idx, wgt);
#pragma unroll
        for (int k = 0; k < 4; ++k) {
            ((int*)&m.off)[k]  = idx[k] * C_IN;
            ((float*)&m.w)[k]  = wgt[k];
        }
        m.off.x |= (nc - 2);
        cmeta[slot * 7 + ox] = m;
    }
}

// ---------------- gather: nr*nc unique corners ------------------------------
template<int NR, int NC>
__device__ __forceinline__ f32x4 gather(const float* __restrict__ base,
                                        const int* ro, const int* co,
                                        const float* wr, const float* wc,
                                        int c4)
{
    f32x4 v[NR * NC];
#pragma unroll
    for (int i = 0; i < NR; ++i)
#pragma unroll
        for (int j = 0; j < NC; ++j)
            v[i * NC + j] = *(const f32x4*)(base + (size_t)(ro[i] + co[j] + c4));

    f32x4 acc = {0.f, 0.f, 0.f, 0.f};
#pragma unroll
    for (int i = 0; i < NR; ++i)
#pragma unroll
        for (int j = 0; j < NC; ++j)
            acc += v[i * NC + j] * (wr[i] * wc[j]);
    return acc;
}

// ---------------- kernel B: one wave per output pixel ----------------------
__global__ __launch_bounds__(256) void roi_align_kernel(
    const float* __restrict__ inputs,
    const int*   __restrict__ perm,
    const Meta*  __restrict__ rmeta,
    const Meta*  __restrict__ cmeta,
    float*       __restrict__ out)
{
    const int lane = threadIdx.x & 63;
    const int sub  = __builtin_amdgcn_readfirstlane(threadIdx.x >> 6);  // wave-uniform

    // XCD-chunked swizzle: grid = 12544 (div by 8); consecutive sorted pixels
    // (same/neighbor boxes) land on the same XCD.
    const int nchunk = gridDim.x >> 3;
    const int lbid   = (blockIdx.x & 7) * nchunk + (blockIdx.x >> 3);
    const int p      = lbid * 4 + sub;           // sorted pixel id [0, 50176)

    const int bs  = p / NPIX;                    // sorted box slot
    const int rem = p - bs * NPIX;
    const int oy  = (rem * 37) >> 8;             // exact /7 for 0..48
    const int ox  = rem - oy * 7;

    const int b = __builtin_amdgcn_readfirstlane(perm[bs]);   // real box id

    Meta rm = rmeta[bs * 7 + oy];                // 32 B uniform load
    Meta cm = cmeta[bs * 7 + ox];                // 32 B uniform load

    const int sel = __builtin_amdgcn_readfirstlane(
        (rm.off.x & 3) * 3 + (cm.off.x & 3));
    rm.off.x &= ~3;
    cm.off.x &= ~3;

    const int* ro   = (const int*)&rm.off;
    const float* wr = (const float*)&rm.w;
    const int* co   = (const int*)&cm.off;
    const float* wc = (const float*)&cm.w;
    const int c4 = lane * 4;

    f32x4 acc;
    switch (sel) {
        case 0: acc = gather<2, 2>(inputs, ro, co, wr, wc, c4); break;
        case 1: acc = gather<2, 3>(inputs, ro, co, wr, wc, c4); break;
        case 2: acc = gather<2, 4>(inputs, ro, co, wr, wc, c4); break;
        case 3: acc = gather<3, 2>(inputs, ro, co, wr, wc, c4); break;
        case 4: acc = gather<3, 3>(inputs, ro, co, wr, wc, c4); break;
        case 5: acc = gather<3, 4>(inputs, ro, co, wr, wc, c4); break;
        case 6: acc = gather<4, 2>(inputs, ro, co, wr, wc, c4); break;
        case 7: acc = gather<4, 3>(inputs, ro, co, wr, wc, c4); break;
        default: acc = gather<4, 4>(inputs, ro, co, wr, wc, c4); break;
    }

    float* op = out + ((size_t)b * NPIX + rem) * C_IN + c4;
    __builtin_nontemporal_store(acc, (f32x4*)op);
}

extern "C" void kernel_launch(void* const* d_in, const int* in_sizes, int n_in,
                              void* d_out, int out_size, void* d_ws, size_t ws_size,
                              hipStream_t stream) {
    const float* inputs   = (const float*)d_in[0];
    const float* boxes    = (const float*)d_in[1];
    const int*   box_inds = (const int*)d_in[2];
    float*       out      = (float*)d_out;

    int*  perm  = (int*)d_ws;
    Meta* rmeta = (Meta*)((char*)d_ws + RMETA_OFF);
    Meta* cmeta = (Meta*)((char*)d_ws + CMETA_OFF);

    sort_boxes_kernel<<<1, NBOX, 0, stream>>>(boxes, box_inds, perm);
    meta_kernel<<<56, 256, 0, stream>>>(boxes, box_inds, perm, rmeta, cmeta);

    const int blocks = NBOX * NPIX / 4;          // 12544
    roi_align_kernel<<<blocks, 256, 0, stream>>>(inputs, perm, rmeta, cmeta, out);
}